// Round 15
// baseline (212.465 us; speedup 1.0000x reference)
//
#include <hip/hip_runtime.h>
#include <stdint.h>

#define M_ROWS 65536
#define C_DIM  256
#define K_CLS  20
#define P_POS  2048
#define MARGIN_F 0.3f
#define EPS_D (0.0001f / 256.0f)
#define SCALE1 0x7F7F7F7Fu   /* e8m0 127 = 2^0 in all four bytes */

typedef float floatx4 __attribute__((ext_vector_type(4)));
typedef int   intx8   __attribute__((ext_vector_type(8)));
union Frag8 { intx8 v; uint4 q[2]; };

__device__ __forceinline__ float sigm(float x) { return 1.f / (1.f + __expf(-x)); }

// ------- Kernel 1: sigmoid -> fp8 e4m3 table + fp8-exact row norms ----------
// Also inits the hp/hn merge keys (argmax init 0, argmin init ~0).
__global__ __launch_bounds__(256) void sigmoid_norm_k(
        const float* __restrict__ feat,
        unsigned int* __restrict__ S8,     // [M][64] uint = 256 fp8/row
        float* __restrict__ xx,
        unsigned int* __restrict__ hp,
        unsigned int* __restrict__ hn) {
    {
        const int idx = blockIdx.x * 256 + threadIdx.x;
        if (idx < K_CLS * P_POS) { hp[idx] = 0u; hn[idx] = 0xFFFFFFFFu; }
    }
    const int wave = threadIdx.x >> 6, lane = threadIdx.x & 63;
    const int row = blockIdx.x * 4 + wave;
    const float4 v = *(const float4*)(feat + (size_t)row * C_DIM + lane * 4);

    const int p01 = __builtin_amdgcn_cvt_pk_fp8_f32(sigm(v.x), sigm(v.y), 0, false);
    const int p23 = __builtin_amdgcn_cvt_pk_fp8_f32(sigm(v.z), sigm(v.w), 0, false);
    const unsigned int packed = (unsigned int)(p01 & 0xFFFF) | ((unsigned int)p23 << 16);
    S8[(size_t)row * 64 + lane] = packed;

    const float q0 = __builtin_amdgcn_cvt_f32_fp8(p01, 0);
    const float q1 = __builtin_amdgcn_cvt_f32_fp8(p01, 1);
    const float q2 = __builtin_amdgcn_cvt_f32_fp8(p23, 0);
    const float q3 = __builtin_amdgcn_cvt_f32_fp8(p23, 1);
    float sum = q0 * q0 + q1 * q1 + q2 * q2 + q3 * q3;
#pragma unroll
    for (int off = 32; off; off >>= 1) sum += __shfl_down(sum, off);
    if (lane == 0) xx[row] = sum;
}

// ---------- Kernel 2: BARRIER-FREE MX-fp8 distance-GEMM + arg-select --------
// Structural change vs R14: NO LDS, NO __syncthreads. Each lane gathers its
// B fragment directly from the XCD-L2-resident 512 KB B-set (per ct-half one
// 64-bit base idx*256 + quad*32, then 4 dwordx4 at imm offsets 0/16/128/144).
// B/yv/idx register-pipelined one tile ahead -> waves slip freely; the 16
// per-block barrier drains of R10-R14 (the 4x-over-floor plateau) are gone.
// Wave tile 64i x 32j, mfma_scale_f32_16x16x128_f8f6f4 unit scales, A in 64
// regs. Key enc=(bits(yy-2*x.y)&~2047)|j merged via atomicMax/Min on
// monotone uint keys. Grid 1280 = 8 i_blk x 4 jq x 40 (k,type); bid%40 ->
// same XCD per (k,type). launch_bounds(256,2): ~180-reg footprint, no spill.
__global__ __launch_bounds__(256, 2) void select_k(
        const unsigned int* __restrict__ S8,
        const float* __restrict__ xx,
        const int* __restrict__ pos_idx,
        const int* __restrict__ neg_idx,
        unsigned int* __restrict__ hp,
        unsigned int* __restrict__ hn) {
    const int tid    = threadIdx.x;
    const int w      = tid >> 6;        // 0..3 (i-quarter)
    const int lane   = tid & 63;
    const int lane15 = lane & 15;
    const int quad   = lane >> 4;

    const int bid    = blockIdx.x;      // 1280 = 32 (i_blk,jq) x 40 (k,type)
    const int ctid   = bid % 40;
    const int rest   = bid / 40;        // 0..31
    const int i_blk  = rest >> 2;       // 0..7
    const int jq     = rest & 3;        // 0..3
    const int k      = ctid >> 1;
    const int isNeg  = ctid & 1;
    const int i0     = i_blk * 256;
    const int j0     = jq * 512;        // 16 tiles of 32 j

    const int* __restrict__ idxA = pos_idx + k * P_POS;
    const int* __restrict__ idxB = (isNeg ? neg_idx : pos_idx) + k * P_POS;
    unsigned int* outKey         = (isNeg ? hn : hp) + k * P_POS;

    const char* S8B = (const char*)S8;          // row stride 256 B

    // ---- A fragments: row i0+w*64+si*16+lane15, k0 = quad*32 + s*128 ----
    Frag8 A_reg[4][2];
#pragma unroll
    for (int si = 0; si < 4; ++si) {
        const int gi = idxA[i0 + w * 64 + si * 16 + lane15];
        const char* rb = S8B + ((size_t)(uint32_t)gi << 8) + quad * 32;
#pragma unroll
        for (int s = 0; s < 2; ++s) {
            A_reg[si][s].q[0] = *(const uint4*)(rb + s * 128);
            A_reg[si][s].q[1] = *(const uint4*)(rb + s * 128 + 16);
        }
    }

    // ---- warmup: tile-0 B rows + yv; tile-1 indices ----
    int i_c0 = idxB[j0 + lane15];
    int i_c1 = idxB[j0 + 16 + lane15];
    float yv0 = xx[i_c0];
    float yv1 = xx[i_c1];
    Frag8 cur[2][2];
    {
        const char* b0 = S8B + ((size_t)(uint32_t)i_c0 << 8) + quad * 32;
        const char* b1 = S8B + ((size_t)(uint32_t)i_c1 << 8) + quad * 32;
#pragma unroll
        for (int s = 0; s < 2; ++s) {
            cur[0][s].q[0] = *(const uint4*)(b0 + s * 128);
            cur[0][s].q[1] = *(const uint4*)(b0 + s * 128 + 16);
            cur[1][s].q[0] = *(const uint4*)(b1 + s * 128);
            cur[1][s].q[1] = *(const uint4*)(b1 + s * 128 + 16);
        }
    }
    int idx_n0 = idxB[j0 + 32 + lane15];
    int idx_n1 = idxB[j0 + 48 + lane15];

    float bestv[16];
    const float binit = isNeg ? 3.4e38f : -3.4e38f;
#pragma unroll
    for (int t = 0; t < 16; ++t) bestv[t] = binit;

#pragma unroll 2
    for (int jc = 0; jc < 16; ++jc) {
        // ---- prefetch tile jc+1: B fragments + yv (idx loaded last iter) --
        Frag8 nb[2][2];
        const char* b0 = S8B + ((size_t)(uint32_t)idx_n0 << 8) + quad * 32;
        const char* b1 = S8B + ((size_t)(uint32_t)idx_n1 << 8) + quad * 32;
#pragma unroll
        for (int s = 0; s < 2; ++s) {
            nb[0][s].q[0] = *(const uint4*)(b0 + s * 128);
            nb[0][s].q[1] = *(const uint4*)(b0 + s * 128 + 16);
            nb[1][s].q[0] = *(const uint4*)(b1 + s * 128);
            nb[1][s].q[1] = *(const uint4*)(b1 + s * 128 + 16);
        }
        const float nv0 = xx[idx_n0];
        const float nv1 = xx[idx_n1];
        // refill indices for tile jc+2 (clamped; dead work on last iters)
        {
            const int nt = j0 + (jc < 14 ? jc + 2 : 15) * 32;
            idx_n0 = idxB[nt + lane15];
            idx_n1 = idxB[nt + 16 + lane15];
        }

        // ---- compute: 2 K-steps of 128; 8 MFMAs from registers ----
        floatx4 acc[2][4];
#pragma unroll
        for (int ct = 0; ct < 2; ++ct)
#pragma unroll
            for (int si = 0; si < 4; ++si)
                acc[ct][si] = (floatx4){0.f, 0.f, 0.f, 0.f};

#pragma unroll
        for (int s = 0; s < 2; ++s) {
#pragma unroll
            for (int si = 0; si < 4; ++si)
                acc[0][si] = __builtin_amdgcn_mfma_scale_f32_16x16x128_f8f6f4(
                    A_reg[si][s].v, cur[0][s].v, acc[0][si], 0, 0,
                    0, SCALE1, 0, SCALE1);
#pragma unroll
            for (int si = 0; si < 4; ++si)
                acc[1][si] = __builtin_amdgcn_mfma_scale_f32_16x16x128_f8f6f4(
                    A_reg[si][s].v, cur[1][s].v, acc[1][si], 0, 0,
                    0, SCALE1, 0, SCALE1);
        }

        // ---- epilogue: enc = (bits(g) & ~2047) | j; single max/min ----
        const uint32_t jb0 = (uint32_t)((j0 + (jc << 5)) | lane15);
        const uint32_t jb1 = jb0 | 16u;
#pragma unroll
        for (int ct = 0; ct < 2; ++ct) {
            const float yv = ct ? yv1 : yv0;
            const uint32_t jb = ct ? jb1 : jb0;
#pragma unroll
            for (int si = 0; si < 4; ++si)
#pragma unroll
                for (int r = 0; r < 4; ++r) {
                    const float g = fmaf(-2.f, acc[ct][si][r], yv);
                    const float enc = __uint_as_float(
                        (__float_as_uint(g) & 0xFFFFF800u) | jb);
                    const int slot = si * 4 + r;
                    bestv[slot] = isNeg ? fminf(bestv[slot], enc)
                                        : fmaxf(bestv[slot], enc);
                }
        }

        // rotate pipeline registers (renamed away by unroll-2)
#pragma unroll
        for (int ct = 0; ct < 2; ++ct)
#pragma unroll
            for (int s = 0; s < 2; ++s) cur[ct][s] = nb[ct][s];
        yv0 = nv0; yv1 = nv1;
    }

    // ---- reduce over the 16 column-lanes (index rides in the bits) ----
#pragma unroll
    for (int slot = 0; slot < 16; ++slot) {
#pragma unroll
        for (int off = 1; off < 16; off <<= 1) {
            const float ov = __shfl_xor(bestv[slot], off);
            bestv[slot] = isNeg ? fminf(bestv[slot], ov) : fmaxf(bestv[slot], ov);
        }
    }
    // ---- merge across j-quarters: monotone-mapped key + device atomics ----
    if (lane15 == 0) {
#pragma unroll
        for (int si = 0; si < 4; ++si)
#pragma unroll
            for (int r = 0; r < 4; ++r) {
                const int row = w * 64 + si * 16 + quad * 4 + r;
                const uint32_t u = __float_as_uint(bestv[si * 4 + r]);
                const uint32_t key = (u & 0x80000000u) ? ~u : (u | 0x80000000u);
                if (isNeg) atomicMin(&outKey[i0 + row], key);
                else       atomicMax(&outKey[i0 + row], key);
            }
    }
}

// ------- Kernel 3: per-anchor pdist from fp8 table (16 lanes/anchor) --------
#define ACC16(UA, UP, UN)                                                     \
    {                                                                         \
        float xa, d;                                                          \
        xa = __builtin_amdgcn_cvt_f32_fp8((int)(UA), 0);                      \
        d = xa - __builtin_amdgcn_cvt_f32_fp8((int)(UP), 0); dp += d * d;     \
        d = xa - __builtin_amdgcn_cvt_f32_fp8((int)(UN), 0); dn += d * d;     \
        xa = __builtin_amdgcn_cvt_f32_fp8((int)(UA), 1);                      \
        d = xa - __builtin_amdgcn_cvt_f32_fp8((int)(UP), 1); dp += d * d;     \
        d = xa - __builtin_amdgcn_cvt_f32_fp8((int)(UN), 1); dn += d * d;     \
        xa = __builtin_amdgcn_cvt_f32_fp8((int)(UA), 2);                      \
        d = xa - __builtin_amdgcn_cvt_f32_fp8((int)(UP), 2); dp += d * d;     \
        d = xa - __builtin_amdgcn_cvt_f32_fp8((int)(UN), 2); dn += d * d;     \
        xa = __builtin_amdgcn_cvt_f32_fp8((int)(UA), 3);                      \
        d = xa - __builtin_amdgcn_cvt_f32_fp8((int)(UP), 3); dp += d * d;     \
        d = xa - __builtin_amdgcn_cvt_f32_fp8((int)(UN), 3); dn += d * d;     \
    }

__global__ __launch_bounds__(256) void loss_k(
        const unsigned int* __restrict__ S8,
        const int* __restrict__ pos_idx,
        const int* __restrict__ neg_idx,
        const unsigned int* __restrict__ hp,
        const unsigned int* __restrict__ hn,
        float* __restrict__ terms) {
    const int tid    = threadIdx.x;
    const int lane15 = tid & 15;
    const int grp    = tid >> 4;               // 0..15: anchor group in block
    const int a      = blockIdx.x * 16 + grp;  // 2048%16==0 -> one class/block
    const int k      = a >> 11;
    const int i      = a & 2047;
    const int* pidx = pos_idx + (k << 11);
    const int* nidx = neg_idx + (k << 11);
    const unsigned int kp = hp[a], kn = hn[a];
    const int jp = (int)((kp & 0x80000000u) ? (kp & 2047u) : ((~kp) & 2047u));
    const int jn = (int)((kn & 0x80000000u) ? (kn & 2047u) : ((~kn) & 2047u));
    const int ga = pidx[i];
    const int gp = pidx[jp];
    const int gn = nidx[jn];

    const char* S8B = (const char*)S8;
    const uint4 va = *(const uint4*)(S8B + ((size_t)(uint32_t)ga << 8) + lane15 * 16);
    const uint4 vp = *(const uint4*)(S8B + ((size_t)(uint32_t)gp << 8) + lane15 * 16);
    const uint4 vn = *(const uint4*)(S8B + ((size_t)(uint32_t)gn << 8) + lane15 * 16);

    float dp = 0.f, dn = 0.f;
    ACC16(va.x, vp.x, vn.x)
    ACC16(va.y, vp.y, vn.y)
    ACC16(va.z, vp.z, vn.z)
    ACC16(va.w, vp.w, vn.w)

#pragma unroll
    for (int off = 1; off < 16; off <<= 1) {   // xor stays within 16-lane group
        dp += __shfl_xor(dp, off);
        dn += __shfl_xor(dn, off);
    }
    if (lane15 == 0) {
        const float d_p = sqrtf(fmaxf(dp, 0.f) + EPS_D);
        const float d_n = sqrtf(fmaxf(dn, 0.f) + EPS_D);
        terms[a] = fmaxf(MARGIN_F + d_p - d_n, 0.f);
    }
}

// ---------------- Kernel 4: final reduction (sum of class means) ------------
__global__ __launch_bounds__(1024) void reduce_k(
        const float* __restrict__ terms, float* __restrict__ out) {
    __shared__ float red[1024];
    float s = 0.f;
    for (int i = threadIdx.x; i < K_CLS * P_POS; i += 1024) s += terms[i];
    red[threadIdx.x] = s;
    __syncthreads();
    for (int off = 512; off; off >>= 1) {
        if ((int)threadIdx.x < off) red[threadIdx.x] += red[threadIdx.x + off];
        __syncthreads();
    }
    if (threadIdx.x == 0) out[0] = red[0] * (1.0f / (float)P_POS);
}

extern "C" void kernel_launch(void* const* d_in, const int* in_sizes, int n_in,
                              void* d_out, int out_size, void* d_ws, size_t ws_size,
                              hipStream_t stream) {
    const float* feat    = (const float*)d_in[0];
    const int*   pos_idx = (const int*)d_in[1];
    const int*   neg_idx = (const int*)d_in[2];

    char* ws = (char*)d_ws;
    unsigned int* S8 = (unsigned int*)ws;                     // 16 MiB fp8 table
    float*        xx = (float*)(ws + 16777216);               // 256 KiB norms
    unsigned int* hp = (unsigned int*)(ws + 17039360);        // 160 KiB keys
    unsigned int* hn = (unsigned int*)(ws + 17203200);        // 160 KiB keys
    float*     terms = (float*)(ws + 17367040);               // 160 KiB

    sigmoid_norm_k<<<M_ROWS / 4, 256, 0, stream>>>(feat, S8, xx, hp, hn);

    select_k<<<32 * 40, 256, 0, stream>>>(S8, xx, pos_idx, neg_idx, hp, hn);

    loss_k<<<(K_CLS * P_POS) / 16, 256, 0, stream>>>(S8, pos_idx, neg_idx, hp, hn, terms);

    reduce_k<<<1, 1024, 0, stream>>>(terms, (float*)d_out);
}

// Round 16
// 173.871 us; speedup vs baseline: 1.2220x; 1.2220x over previous
//
#include <hip/hip_runtime.h>
#include <stdint.h>

#define M_ROWS 65536
#define C_DIM  256
#define K_CLS  20
#define P_POS  2048
#define MARGIN_F 0.3f
#define EPS_D (0.0001f / 256.0f)
#define SCALE1 0x7F7F7F7Fu   /* e8m0 127 = 2^0 in all four bytes */

typedef float floatx4 __attribute__((ext_vector_type(4)));
typedef int   intx8   __attribute__((ext_vector_type(8)));
union Frag8 { intx8 v; uint4 q[2]; };

// async 16B/lane global -> LDS (wave-uniform LDS base + lane*16)
__device__ __forceinline__ void async_copy16(const void* g, void* l) {
    __builtin_amdgcn_global_load_lds(
        (const __attribute__((address_space(1))) void*)g,
        (__attribute__((address_space(3))) void*)l, 16, 0, 0);
}
__device__ __forceinline__ float sigm(float x) { return 1.f / (1.f + __expf(-x)); }

// ------- Kernel 1: sigmoid -> fp8 e4m3 table + fp8-exact row norms ----------
// Also inits the hp/hn merge keys (argmax init 0, argmin init ~0).
__global__ __launch_bounds__(256) void sigmoid_norm_k(
        const float* __restrict__ feat,
        unsigned int* __restrict__ S8,     // [M][64] uint = 256 fp8/row
        float* __restrict__ xx,
        unsigned int* __restrict__ hp,
        unsigned int* __restrict__ hn) {
    {
        const int idx = blockIdx.x * 256 + threadIdx.x;
        if (idx < K_CLS * P_POS) { hp[idx] = 0u; hn[idx] = 0xFFFFFFFFu; }
    }
    const int wave = threadIdx.x >> 6, lane = threadIdx.x & 63;
    const int row = blockIdx.x * 4 + wave;
    const float4 v = *(const float4*)(feat + (size_t)row * C_DIM + lane * 4);

    const int p01 = __builtin_amdgcn_cvt_pk_fp8_f32(sigm(v.x), sigm(v.y), 0, false);
    const int p23 = __builtin_amdgcn_cvt_pk_fp8_f32(sigm(v.z), sigm(v.w), 0, false);
    const unsigned int packed = (unsigned int)(p01 & 0xFFFF) | ((unsigned int)p23 << 16);
    S8[(size_t)row * 64 + lane] = packed;

    const float q0 = __builtin_amdgcn_cvt_f32_fp8(p01, 0);
    const float q1 = __builtin_amdgcn_cvt_f32_fp8(p01, 1);
    const float q2 = __builtin_amdgcn_cvt_f32_fp8(p23, 0);
    const float q3 = __builtin_amdgcn_cvt_f32_fp8(p23, 1);
    float sum = q0 * q0 + q1 * q1 + q2 * q2 + q3 * q3;
#pragma unroll
    for (int off = 32; off; off >>= 1) sum += __shfl_down(sum, off);
    if (lane == 0) xx[row] = sum;
}

// ---------- Kernel 2: fused MX-fp8 (K=128) distance-GEMM + arg-select -------
// R14/R11 structure (best known) + yy LDS table (kills the 4 per-tile in-loop
// dependent gathers; R15 proved the LDS-staged B path beats per-lane gathers:
// scattered dwordx4 serializes the TA pipe and loses intra-block B sharing).
// Block 256i x 32j-tile, 4 waves in i; wave tile 64i x 32j. MFMA =
// mfma_scale_f32_16x16x128_f8f6f4, unit scales. A (64 x 256 fp8) in 64 regs;
// B double-buffered 2 x 8 KB via global_load_lds with 16B-chunk XOR swizzle
// (0 bank conflicts measured). yyL[512] = xx of this j-quarter, loaded once.
// Key: enc=(bits(yy-2*x.y)&~2047)|j, merged via atomicMax/Min on monotone
// uint keys (2048-entry arrays -> no cacheline hotspot; NEVER funnel atomics
// into one line: R13's 20-cell cls[] cost 240 us).
// Grid 1280 = 8 i_blk x 4 jq x 40 (k,type); bid%40 -> same XCD per (k,type).
__global__ __launch_bounds__(256, 3) void select_k(
        const unsigned int* __restrict__ S8,
        const float* __restrict__ xx,
        const int* __restrict__ pos_idx,
        const int* __restrict__ neg_idx,
        unsigned int* __restrict__ hp,
        unsigned int* __restrict__ hn) {
    __shared__ __align__(16) unsigned char Bt[2][32 * 256];   // 16 KiB
    __shared__ float yyL[512];                                // 2 KiB

    const int tid    = threadIdx.x;
    const int w      = tid >> 6;        // 0..3 (i-quarter)
    const int lane   = tid & 63;
    const int lane15 = lane & 15;
    const int quad   = lane >> 4;

    const int bid    = blockIdx.x;      // 1280 = 32 (i_blk,jq) x 40 (k,type)
    const int ctid   = bid % 40;
    const int rest   = bid / 40;        // 0..31
    const int i_blk  = rest >> 2;       // 0..7
    const int jq     = rest & 3;        // 0..3
    const int k      = ctid >> 1;
    const int isNeg  = ctid & 1;
    const int i0     = i_blk * 256;
    const int j0     = jq * 512;        // 16 tiles of 32 j

    const int* __restrict__ idxA = pos_idx + k * P_POS;
    const int* __restrict__ idxB = (isNeg ? neg_idx : pos_idx) + k * P_POS;
    unsigned int* outKey         = (isNeg ? hn : hp) + k * P_POS;

    const char* S8B = (const char*)S8;          // row stride 256 B

    // ---- staging geometry: 8 ops/tile (2 per wave), 4 rows per op ----
    const int rl  = lane >> 4;          // 0..3
    const int cch = lane & 15;
    int rloc[2], soff[2];
#pragma unroll
    for (int c = 0; c < 2; ++c) {
        rloc[c] = (w * 2 + c) * 4 + rl;                  // tile-local row
        soff[c] = (cch ^ (rloc[c] & 15)) << 4;           // swizzled source chunk
    }

    // ---- stage tile 0 into Bt[0] ----
    int g_st[2];
#pragma unroll
    for (int c = 0; c < 2; ++c) g_st[c] = idxB[j0 + rloc[c]];
#pragma unroll
    for (int c = 0; c < 2; ++c)
        async_copy16(S8B + ((size_t)(uint32_t)g_st[c] << 8) + soff[c],
                     (char*)&Bt[0][0] + (w * 2 + c) * 1024);
#pragma unroll
    for (int c = 0; c < 2; ++c) g_st[c] = idxB[j0 + 32 + rloc[c]];

    // ---- yy table for this j-quarter, once per block (2 gathers/thread) ----
#pragma unroll
    for (int t = 0; t < 2; ++t) {
        const int jj = t * 256 + tid;
        yyL[jj] = xx[idxB[j0 + jj]];
    }

    // ---- A fragments: row i0+w*64+si*16+lane15, k0 = quad*32 + s*128 ----
    Frag8 A_reg[4][2];
#pragma unroll
    for (int si = 0; si < 4; ++si) {
        const int gi = idxA[i0 + w * 64 + si * 16 + lane15];
        const char* rb = S8B + ((size_t)(uint32_t)gi << 8) + quad * 32;
#pragma unroll
        for (int s = 0; s < 2; ++s) {
            A_reg[si][s].q[0] = *(const uint4*)(rb + s * 128);
            A_reg[si][s].q[1] = *(const uint4*)(rb + s * 128 + 16);
        }
    }

    // ---- LDS read offsets: global chunks c0 = s*8 + quad*2, c0+1;
    //      LDS position = chunk ^ (row & 15) = chunk ^ lane15 ----
    int blo[2], bhi[2];
#pragma unroll
    for (int s = 0; s < 2; ++s) {
        const int c0 = s * 8 + quad * 2;
        blo[s] = lane15 * 256 + ((c0 ^ lane15) << 4);
        bhi[s] = lane15 * 256 + (((c0 + 1) ^ lane15) << 4);
    }

    float bestv[16];
    const float binit = isNeg ? 3.4e38f : -3.4e38f;
#pragma unroll
    for (int t = 0; t < 16; ++t) bestv[t] = binit;

#pragma unroll 2
    for (int jc = 0; jc < 16; ++jc) {
        __syncthreads();   // prev readers done + this tile's loads drained
                           // (also covers the yyL fill before first use)

        // yv: LDS broadcast (same address across the quad -> conflict-free)
        const float yv0 = yyL[(jc << 5) + lane15];
        const float yv1 = yyL[(jc << 5) + 16 + lane15];

        // stage tile jc+1 into the other buffer
        if (jc < 15) {
            char* lb = (char*)(&Bt[(jc + 1) & 1][0]);
#pragma unroll
            for (int c = 0; c < 2; ++c)
                async_copy16(S8B + ((size_t)(uint32_t)g_st[c] << 8) + soff[c],
                             lb + (w * 2 + c) * 1024);
        }
        // refill staging indices for tile jc+2 (clamped; dead on last iters)
        {
            const int nt = j0 + (jc < 14 ? jc + 2 : 15) * 32;
#pragma unroll
            for (int c = 0; c < 2; ++c) g_st[c] = idxB[nt + rloc[c]];
        }

        // ---- compute: 2 K-steps of 128; 4 b128 B-reads feed 8 MFMAs ----
        const char* Bb = (const char*)(&Bt[jc & 1][0]);
        floatx4 acc[2][4];
#pragma unroll
        for (int ct = 0; ct < 2; ++ct)
#pragma unroll
            for (int si = 0; si < 4; ++si)
                acc[ct][si] = (floatx4){0.f, 0.f, 0.f, 0.f};

#pragma unroll
        for (int s = 0; s < 2; ++s) {
            Frag8 bf0, bf1;
            bf0.q[0] = *(const uint4*)(Bb + blo[s]);
            bf0.q[1] = *(const uint4*)(Bb + bhi[s]);
            bf1.q[0] = *(const uint4*)(Bb + blo[s] + 4096);
            bf1.q[1] = *(const uint4*)(Bb + bhi[s] + 4096);
#pragma unroll
            for (int si = 0; si < 4; ++si)
                acc[0][si] = __builtin_amdgcn_mfma_scale_f32_16x16x128_f8f6f4(
                    A_reg[si][s].v, bf0.v, acc[0][si], 0, 0,
                    0, SCALE1, 0, SCALE1);
#pragma unroll
            for (int si = 0; si < 4; ++si)
                acc[1][si] = __builtin_amdgcn_mfma_scale_f32_16x16x128_f8f6f4(
                    A_reg[si][s].v, bf1.v, acc[1][si], 0, 0,
                    0, SCALE1, 0, SCALE1);
        }

        // ---- epilogue: enc = (bits(g) & ~2047) | j; single max/min ----
        const uint32_t jb0 = (uint32_t)((j0 + (jc << 5)) | lane15);
        const uint32_t jb1 = jb0 | 16u;
#pragma unroll
        for (int ct = 0; ct < 2; ++ct) {
            const float yv = ct ? yv1 : yv0;
            const uint32_t jb = ct ? jb1 : jb0;
#pragma unroll
            for (int si = 0; si < 4; ++si)
#pragma unroll
                for (int r = 0; r < 4; ++r) {
                    const float g = fmaf(-2.f, acc[ct][si][r], yv);
                    const float enc = __uint_as_float(
                        (__float_as_uint(g) & 0xFFFFF800u) | jb);
                    const int slot = si * 4 + r;
                    bestv[slot] = isNeg ? fminf(bestv[slot], enc)
                                        : fmaxf(bestv[slot], enc);
                }
        }
    }

    // ---- reduce over the 16 column-lanes (index rides in the bits) ----
#pragma unroll
    for (int slot = 0; slot < 16; ++slot) {
#pragma unroll
        for (int off = 1; off < 16; off <<= 1) {
            const float ov = __shfl_xor(bestv[slot], off);
            bestv[slot] = isNeg ? fminf(bestv[slot], ov) : fmaxf(bestv[slot], ov);
        }
    }
    // ---- merge across j-quarters: monotone-mapped key + device atomics ----
    if (lane15 == 0) {
#pragma unroll
        for (int si = 0; si < 4; ++si)
#pragma unroll
            for (int r = 0; r < 4; ++r) {
                const int row = w * 64 + si * 16 + quad * 4 + r;
                const uint32_t u = __float_as_uint(bestv[si * 4 + r]);
                const uint32_t key = (u & 0x80000000u) ? ~u : (u | 0x80000000u);
                if (isNeg) atomicMin(&outKey[i0 + row], key);
                else       atomicMax(&outKey[i0 + row], key);
            }
    }
}

// ------- Kernel 3: per-anchor pdist from fp8 table (16 lanes/anchor) --------
#define ACC16(UA, UP, UN)                                                     \
    {                                                                         \
        float xa, d;                                                          \
        xa = __builtin_amdgcn_cvt_f32_fp8((int)(UA), 0);                      \
        d = xa - __builtin_amdgcn_cvt_f32_fp8((int)(UP), 0); dp += d * d;     \
        d = xa - __builtin_amdgcn_cvt_f32_fp8((int)(UN), 0); dn += d * d;     \
        xa = __builtin_amdgcn_cvt_f32_fp8((int)(UA), 1);                      \
        d = xa - __builtin_amdgcn_cvt_f32_fp8((int)(UP), 1); dp += d * d;     \
        d = xa - __builtin_amdgcn_cvt_f32_fp8((int)(UN), 1); dn += d * d;     \
        xa = __builtin_amdgcn_cvt_f32_fp8((int)(UA), 2);                      \
        d = xa - __builtin_amdgcn_cvt_f32_fp8((int)(UP), 2); dp += d * d;     \
        d = xa - __builtin_amdgcn_cvt_f32_fp8((int)(UN), 2); dn += d * d;     \
        xa = __builtin_amdgcn_cvt_f32_fp8((int)(UA), 3);                      \
        d = xa - __builtin_amdgcn_cvt_f32_fp8((int)(UP), 3); dp += d * d;     \
        d = xa - __builtin_amdgcn_cvt_f32_fp8((int)(UN), 3); dn += d * d;     \
    }

__global__ __launch_bounds__(256) void loss_k(
        const unsigned int* __restrict__ S8,
        const int* __restrict__ pos_idx,
        const int* __restrict__ neg_idx,
        const unsigned int* __restrict__ hp,
        const unsigned int* __restrict__ hn,
        float* __restrict__ terms) {
    const int tid    = threadIdx.x;
    const int lane15 = tid & 15;
    const int grp    = tid >> 4;               // 0..15: anchor group in block
    const int a      = blockIdx.x * 16 + grp;  // 2048%16==0 -> one class/block
    const int k      = a >> 11;
    const int i      = a & 2047;
    const int* pidx = pos_idx + (k << 11);
    const int* nidx = neg_idx + (k << 11);
    const unsigned int kp = hp[a], kn = hn[a];
    const int jp = (int)((kp & 0x80000000u) ? (kp & 2047u) : ((~kp) & 2047u));
    const int jn = (int)((kn & 0x80000000u) ? (kn & 2047u) : ((~kn) & 2047u));
    const int ga = pidx[i];
    const int gp = pidx[jp];
    const int gn = nidx[jn];

    const char* S8B = (const char*)S8;
    const uint4 va = *(const uint4*)(S8B + ((size_t)(uint32_t)ga << 8) + lane15 * 16);
    const uint4 vp = *(const uint4*)(S8B + ((size_t)(uint32_t)gp << 8) + lane15 * 16);
    const uint4 vn = *(const uint4*)(S8B + ((size_t)(uint32_t)gn << 8) + lane15 * 16);

    float dp = 0.f, dn = 0.f;
    ACC16(va.x, vp.x, vn.x)
    ACC16(va.y, vp.y, vn.y)
    ACC16(va.z, vp.z, vn.z)
    ACC16(va.w, vp.w, vn.w)

#pragma unroll
    for (int off = 1; off < 16; off <<= 1) {   // xor stays within 16-lane group
        dp += __shfl_xor(dp, off);
        dn += __shfl_xor(dn, off);
    }
    if (lane15 == 0) {
        const float d_p = sqrtf(fmaxf(dp, 0.f) + EPS_D);
        const float d_n = sqrtf(fmaxf(dn, 0.f) + EPS_D);
        terms[a] = fmaxf(MARGIN_F + d_p - d_n, 0.f);
    }
}

// ---------------- Kernel 4: final reduction (sum of class means) ------------
__global__ __launch_bounds__(1024) void reduce_k(
        const float* __restrict__ terms, float* __restrict__ out) {
    __shared__ float red[1024];
    float s = 0.f;
    for (int i = threadIdx.x; i < K_CLS * P_POS; i += 1024) s += terms[i];
    red[threadIdx.x] = s;
    __syncthreads();
    for (int off = 512; off; off >>= 1) {
        if ((int)threadIdx.x < off) red[threadIdx.x] += red[threadIdx.x + off];
        __syncthreads();
    }
    if (threadIdx.x == 0) out[0] = red[0] * (1.0f / (float)P_POS);
}

extern "C" void kernel_launch(void* const* d_in, const int* in_sizes, int n_in,
                              void* d_out, int out_size, void* d_ws, size_t ws_size,
                              hipStream_t stream) {
    const float* feat    = (const float*)d_in[0];
    const int*   pos_idx = (const int*)d_in[1];
    const int*   neg_idx = (const int*)d_in[2];

    char* ws = (char*)d_ws;
    unsigned int* S8 = (unsigned int*)ws;                     // 16 MiB fp8 table
    float*        xx = (float*)(ws + 16777216);               // 256 KiB norms
    unsigned int* hp = (unsigned int*)(ws + 17039360);        // 160 KiB keys
    unsigned int* hn = (unsigned int*)(ws + 17203200);        // 160 KiB keys
    float*     terms = (float*)(ws + 17367040);               // 160 KiB

    sigmoid_norm_k<<<M_ROWS / 4, 256, 0, stream>>>(feat, S8, xx, hp, hn);

    select_k<<<32 * 40, 256, 0, stream>>>(S8, xx, pos_idx, neg_idx, hp, hn);

    loss_k<<<(K_CLS * P_POS) / 16, 256, 0, stream>>>(S8, pos_idx, neg_idx, hp, hn, terms);

    reduce_k<<<1, 1024, 0, stream>>>(terms, (float*)d_out);
}